// Round 2
// baseline (429.017 us; speedup 1.0000x reference)
//
#include <hip/hip_runtime.h>
#include <cmath>
#include <cstdint>
#include <cstring>

// ---------------------------------------------------------------------------
// eps = jax.random.normal(jax.random.key(42), (4,4)) reproduced on HOST.
// (verified PASS in earlier rounds): counter (0,e), XOR-fold the 2x32
// outputs; bits>>9|0x3f800000 -> [1,2); affine to [nextafter(-1,0), 1);
// sqrt(2)*erfinv.
// ---------------------------------------------------------------------------

static inline uint32_t rotl32(uint32_t v, int r) { return (v << r) | (v >> (32 - r)); }

static void threefry2x32_42(uint32_t x0, uint32_t x1, uint32_t& o0, uint32_t& o1) {
    const uint32_t k0 = 0u, k1 = 42u;
    const uint32_t ks[3] = { k0, k1, k0 ^ k1 ^ 0x1BD11BDAu };
    static const int R[8] = { 13, 15, 26, 6, 17, 29, 16, 24 };
    x0 += ks[0];
    x1 += ks[1];
    for (int g = 1; g <= 5; ++g) {
        const int* rr = &R[((g - 1) & 1) * 4];
        for (int j = 0; j < 4; ++j) {
            x0 += x1;
            x1 = rotl32(x1, rr[j]);
            x1 ^= x0;
        }
        x0 += ks[g % 3];
        x1 += ks[(g + 1) % 3] + (uint32_t)g;
    }
    o0 = x0;
    o1 = x1;
}

static double erfinv_d(double x) {
    float xf = (float)x;
    float w = -logf((1.0f - xf) * (1.0f + xf));
    float p;
    if (w < 5.0f) {
        w -= 2.5f;
        p = 2.81022636e-08f;
        p = fmaf(p, w, 3.43273939e-07f);
        p = fmaf(p, w, -3.5233877e-06f);
        p = fmaf(p, w, -4.39150654e-06f);
        p = fmaf(p, w, 0.00021858087f);
        p = fmaf(p, w, -0.00125372503f);
        p = fmaf(p, w, -0.00417768164f);
        p = fmaf(p, w, 0.246640727f);
        p = fmaf(p, w, 1.50140941f);
    } else {
        w = sqrtf(w) - 3.0f;
        p = -0.000200214257f;
        p = fmaf(p, w, 0.000100950558f);
        p = fmaf(p, w, 0.00134934322f);
        p = fmaf(p, w, -0.00367342844f);
        p = fmaf(p, w, 0.00573950773f);
        p = fmaf(p, w, -0.0076224613f);
        p = fmaf(p, w, 0.00943887047f);
        p = fmaf(p, w, 1.00167406f);
        p = fmaf(p, w, 2.83297682f);
    }
    double y = (double)(p * xf);
    const double c = 1.1283791670955126;
    for (int it = 0; it < 3; ++it) {
        double err = erf(y) - x;
        y -= err / (c * exp(-y * y));
    }
    return y;
}

struct EpsT { float e[16]; };

static void compute_eps(float* e) {
    const float lo = -0.99999994f;
    for (int i = 0; i < 16; ++i) {
        uint32_t a, b;
        threefry2x32_42(0u, (uint32_t)i, a, b);
        uint32_t bits = a ^ b;
        uint32_t fb = (bits >> 9) | 0x3f800000u;
        float f;
        memcpy(&f, &fb, 4);
        float u = f - 1.0f;
        float v = u * 2.0f + lo;
        if (v < lo) v = lo;
        e[i] = (float)(sqrt(2.0) * erfinv_d((double)v));
    }
}

// ---------------------------------------------------------------------------
// Shuffle-free MFMA chain via K-permutation (layouts verified end-to-end):
//   C/D: lane (hv=lane>>5, n=lane&31), reg r -> D[row][n], row=(r&3)+8*(r>>2)+4hv
//   A:   lane (hv, m=lane&31), elem j  -> A[m][k=8hv+j]
//   B:   lane (hv, n=lane&31), elem j  -> B[k=8hv+j][n]
// Layers 2/3 relabel K with sigma(16q+8hv+j)=16q+4hv+8*(j>>2)+(j&3) so reg r of
// the previous C/D is exactly elem j=r&7 of B-fragment q=r>>3 (no cross-lane).
// W3 duplicated into output rows 4-7 so both wave halves hold f=0..3 in regs
// 0-3. Mask folds into the W1 A-frag.
//
// This round (VALU/latency attack — counters showed 16% HBM, 2.7%/SIMD MFMA,
// ~1300 VALU/tile):
//  * branchless i-chains + final cndmask select (lets the 4 chains interleave)
//  * layer-boundary f32->f16 via v_cvt_pkrtz_f16_f32 (full-reg packed writes,
//    8 instrs/boundary instead of cvt+pack insert chains); relu in f32
//  * L3 acc-init uses the live b2v as C (rows >=8 are don't-care; b2v[f] is
//    pre-subtracted inside eb[] = b3 + eps - b2v) -> zero init movs, zero
//    extra registers
//  * b1v/b2v consumed directly as MFMA C operands (no per-chain copies)
// NOTE: cvt_pkrtz returns __fp16 vec2 (NOT _Float16 vec2) — union-pun it.
// ---------------------------------------------------------------------------

typedef _Float16 half8 __attribute__((ext_vector_type(8)));
typedef __fp16  pk2   __attribute__((ext_vector_type(2)));
typedef float floatx16 __attribute__((ext_vector_type(16)));

union H8 { half8 v; pk2 h[4]; };

__global__ __launch_bounds__(256, 5) void scm_mfma(
    const float* __restrict__ z,
    const float* __restrict__ W1, const float* __restrict__ b1,
    const float* __restrict__ W2, const float* __restrict__ b2,
    const float* __restrict__ W3, const float* __restrict__ b3,
    const int* __restrict__ mask,
    float* __restrict__ out, EpsT ep, int B)
{
    const int lane = threadIdx.x & 63;
    const int hv   = lane >> 5;          // wave half
    const int n    = lane & 31;          // batch row in tile / m index
    const int wid  = blockIdx.x * (blockDim.x >> 6) + (threadIdx.x >> 6);
    const int nw   = gridDim.x * (blockDim.x >> 6);
    const int T    = B >> 5;             // 32-row tiles

    int mk[16];
#pragma unroll
    for (int t = 0; t < 16; ++t) mk[t] = mask[t];     // uniform -> s_load
    int cond[4];
#pragma unroll
    for (int i = 0; i < 4; ++i) cond[i] = mk[i] | mk[4 + i] | mk[8 + i] | mk[12 + i];

    // ---- weight A-fragments (f16), built once per wave ----
    half8 w1m[4], w2f[2], w3f[2];
#pragma unroll
    for (int j = 0; j < 8; ++j) {
        const int k = hv * 8 + j;                     // k in [0,16), natural
        const float w = W1[k * 32 + n];               // W1^T[m=n][k]
#pragma unroll
        for (int i = 0; i < 4; ++i)                   // mask[f=k&3=j&3][i]
            w1m[i][j] = mk[(j & 3) * 4 + i] ? (_Float16)w : (_Float16)0.f;
    }
#pragma unroll
    for (int q = 0; q < 2; ++q)
#pragma unroll
        for (int j = 0; j < 8; ++j) {
            const int row = 16 * q + 4 * hv + 8 * (j >> 2) + (j & 3);  // sigma(k)
            w2f[q][j] = (_Float16)W2[row * 32 + n];
            w3f[q][j] = (n < 8) ? (_Float16)W3[row * 4 + (n & 3)] : (_Float16)0.f;
        }

    // ---- biases in C/D layout (consumed directly as MFMA C operands) ----
    floatx16 b1v, b2v;
#pragma unroll
    for (int r = 0; r < 16; ++r) {
        const int h = (r & 3) + 8 * (r >> 2) + 4 * hv;
        b1v[r] = b1[h];
        b2v[r] = b2[h];
    }
    // eb[s*4+f] = b3[f] + eps[owned col][f] - b2v[f]; b2v is the L3 C-init
    // (rows >= 8 of that product are never read), so this exactly cancels.
    float eb[8];
#pragma unroll
    for (int s2 = 0; s2 < 2; ++s2)
#pragma unroll
        for (int f = 0; f < 4; ++f)
            eb[s2 * 4 + f] = b3[f] + ep.e[(2 * hv + s2) * 4 + f] - b2v[f];

    // ---- grid-stride tile loop with z prefetch ----
    int t = wid;
    float4 za = make_float4(0.f, 0.f, 0.f, 0.f), zb = za;
    if (t < T) {
        const float4* p = reinterpret_cast<const float4*>(z + ((size_t)t * 32 + n) * 16) + hv * 2;
        za = p[0]; zb = p[1];                         // z[n][hv*8 .. hv*8+7]
    }
    while (t < T) {
        const int tn = t + nw;
        float4 na = make_float4(0.f, 0.f, 0.f, 0.f), nb = na;
        if (tn < T) {
            const float4* p = reinterpret_cast<const float4*>(z + ((size_t)tn * 32 + n) * 16) + hv * 2;
            na = p[0]; nb = p[1];
        }

        const float zf[8] = { za.x, za.y, za.z, za.w, zb.x, zb.y, zb.z, zb.w };
        H8 bz;                                        // Z^T B-frag, k natural (RNE)
#pragma unroll
        for (int j = 0; j < 8; ++j) bz.v[j] = (_Float16)zf[j];

        float ov[8];                                  // default: f32 passthrough
#pragma unroll
        for (int u = 0; u < 8; ++u) ov[u] = zf[u];

#pragma unroll
        for (int i = 0; i < 4; ++i) {
            // L1: K=16, natural order; C = b1v directly
            floatx16 c1 = __builtin_amdgcn_mfma_f32_32x32x16_f16(w1m[i], bz.v, b1v, 0, 0, 0);
            H8 pa, pb;                                // relu in f32, packed RTZ cvt
#pragma unroll
            for (int jj = 0; jj < 4; ++jj) {
                pa.h[jj] = __builtin_amdgcn_cvt_pkrtz(fmaxf(c1[2 * jj], 0.f),
                                                      fmaxf(c1[2 * jj + 1], 0.f));
                pb.h[jj] = __builtin_amdgcn_cvt_pkrtz(fmaxf(c1[8 + 2 * jj], 0.f),
                                                      fmaxf(c1[8 + 2 * jj + 1], 0.f));
            }
            // L2: K=32 via sigma-permuted W2 rows; C = b2v directly
            floatx16 c2 = __builtin_amdgcn_mfma_f32_32x32x16_f16(w2f[0], pa.v, b2v, 0, 0, 0);
            c2 = __builtin_amdgcn_mfma_f32_32x32x16_f16(w2f[1], pb.v, c2, 0, 0, 0);
            H8 qa, qb;
#pragma unroll
            for (int jj = 0; jj < 4; ++jj) {
                qa.h[jj] = __builtin_amdgcn_cvt_pkrtz(fmaxf(c2[2 * jj], 0.f),
                                                      fmaxf(c2[2 * jj + 1], 0.f));
                qb.h[jj] = __builtin_amdgcn_cvt_pkrtz(fmaxf(c2[8 + 2 * jj], 0.f),
                                                      fmaxf(c2[8 + 2 * jj + 1], 0.f));
            }
            // L3: W3 duplicated into rows 4-7; C = b2v (cancelled via eb)
            floatx16 c3 = __builtin_amdgcn_mfma_f32_32x32x16_f16(w3f[0], qa.v, b2v, 0, 0, 0);
            c3 = __builtin_amdgcn_mfma_f32_32x32x16_f16(w3f[1], qb.v, c3, 0, 0, 0);

            const int  s2 = i & 1;
            const bool ow = ((i >> 1) == hv);         // this half owns cols 2hv,2hv+1
            const bool wr = ow && (cond[i] != 0);
#pragma unroll
            for (int f = 0; f < 4; ++f) {
                const float vv = c3[f] + eb[s2 * 4 + f];
                ov[s2 * 4 + f] = wr ? vv : ov[s2 * 4 + f];
            }
        }

        // all 64 lanes store: lane (hv,n) writes out[n][8hv .. 8hv+7]
        float4* op = reinterpret_cast<float4*>(out + ((size_t)t * 32 + n) * 16 + hv * 8);
        op[0] = make_float4(ov[0], ov[1], ov[2], ov[3]);
        op[1] = make_float4(ov[4], ov[5], ov[6], ov[7]);

        t = tn; za = na; zb = nb;
    }
}

extern "C" void kernel_launch(void* const* d_in, const int* in_sizes, int n_in,
                              void* d_out, int out_size, void* d_ws, size_t ws_size,
                              hipStream_t stream) {
    const float* z  = (const float*)d_in[0];
    // d_in[1] = z_int (dead code in reference)
    const float* W1 = (const float*)d_in[2];
    const float* b1 = (const float*)d_in[3];
    const float* W2 = (const float*)d_in[4];
    const float* b2 = (const float*)d_in[5];
    const float* W3 = (const float*)d_in[6];
    const float* b3 = (const float*)d_in[7];
    const int* mask = (const int*)d_in[8];
    // d_in[9] = I (dead code in reference)
    float* out = (float*)d_out;

    const int B = in_sizes[0] / 16;

    EpsT ep;
    compute_eps(ep.e);   // pure host math, deterministic, capture-safe

    dim3 grid(2048), block(256);   // 8192 waves, grid-stride over B/32 tiles
    hipLaunchKernelGGL(scm_mfma, grid, block, 0, stream,
                       z, W1, b1, W2, b2, W3, b3, mask, out, ep, B);
}

// Round 3
// 201.496 us; speedup vs baseline: 2.1292x; 2.1292x over previous
//
#include <hip/hip_runtime.h>
#include <cmath>
#include <cstdint>
#include <cstring>

// ---------------------------------------------------------------------------
// eps = jax.random.normal(jax.random.key(42), (4,4)) reproduced on HOST.
// (verified PASS in earlier rounds): counter (0,e), XOR-fold the 2x32
// outputs; bits>>9|0x3f800000 -> [1,2); affine to [nextafter(-1,0), 1);
// sqrt(2)*erfinv.
// ---------------------------------------------------------------------------

static inline uint32_t rotl32(uint32_t v, int r) { return (v << r) | (v >> (32 - r)); }

static void threefry2x32_42(uint32_t x0, uint32_t x1, uint32_t& o0, uint32_t& o1) {
    const uint32_t k0 = 0u, k1 = 42u;
    const uint32_t ks[3] = { k0, k1, k0 ^ k1 ^ 0x1BD11BDAu };
    static const int R[8] = { 13, 15, 26, 6, 17, 29, 16, 24 };
    x0 += ks[0];
    x1 += ks[1];
    for (int g = 1; g <= 5; ++g) {
        const int* rr = &R[((g - 1) & 1) * 4];
        for (int j = 0; j < 4; ++j) {
            x0 += x1;
            x1 = rotl32(x1, rr[j]);
            x1 ^= x0;
        }
        x0 += ks[g % 3];
        x1 += ks[(g + 1) % 3] + (uint32_t)g;
    }
    o0 = x0;
    o1 = x1;
}

static double erfinv_d(double x) {
    float xf = (float)x;
    float w = -logf((1.0f - xf) * (1.0f + xf));
    float p;
    if (w < 5.0f) {
        w -= 2.5f;
        p = 2.81022636e-08f;
        p = fmaf(p, w, 3.43273939e-07f);
        p = fmaf(p, w, -3.5233877e-06f);
        p = fmaf(p, w, -4.39150654e-06f);
        p = fmaf(p, w, 0.00021858087f);
        p = fmaf(p, w, -0.00125372503f);
        p = fmaf(p, w, -0.00417768164f);
        p = fmaf(p, w, 0.246640727f);
        p = fmaf(p, w, 1.50140941f);
    } else {
        w = sqrtf(w) - 3.0f;
        p = -0.000200214257f;
        p = fmaf(p, w, 0.000100950558f);
        p = fmaf(p, w, 0.00134934322f);
        p = fmaf(p, w, -0.00367342844f);
        p = fmaf(p, w, 0.00573950773f);
        p = fmaf(p, w, -0.0076224613f);
        p = fmaf(p, w, 0.00943887047f);
        p = fmaf(p, w, 1.00167406f);
        p = fmaf(p, w, 2.83297682f);
    }
    double y = (double)(p * xf);
    const double c = 1.1283791670955126;
    for (int it = 0; it < 3; ++it) {
        double err = erf(y) - x;
        y -= err / (c * exp(-y * y));
    }
    return y;
}

struct EpsT { float e[16]; };

static void compute_eps(float* e) {
    const float lo = -0.99999994f;
    for (int i = 0; i < 16; ++i) {
        uint32_t a, b;
        threefry2x32_42(0u, (uint32_t)i, a, b);
        uint32_t bits = a ^ b;
        uint32_t fb = (bits >> 9) | 0x3f800000u;
        float f;
        memcpy(&f, &fb, 4);
        float u = f - 1.0f;
        float v = u * 2.0f + lo;
        if (v < lo) v = lo;
        e[i] = (float)(sqrt(2.0) * erfinv_d((double)v));
    }
}

// ---------------------------------------------------------------------------
// Shuffle-free MFMA chain via K-permutation (layouts verified end-to-end):
//   C/D: lane (hv=lane>>5, n=lane&31), reg r -> D[row][n], row=(r&3)+8*(r>>2)+4hv
//   A:   lane (hv, m=lane&31), elem j  -> A[m][k=8hv+j]
//   B:   lane (hv, n=lane&31), elem j  -> B[k=8hv+j][n]
// Layers 2/3 relabel K with sigma(16q+8hv+j)=16q+4hv+8*(j>>2)+(j&3) so reg r of
// the previous C/D is exactly elem j=r&7 of B-fragment q=r>>3 (no cross-lane).
// W3 duplicated into output rows 4-7 so both wave halves hold f=0..3 in regs
// 0-3. Mask folds into the W1 A-frag.
//
// Round-2 post-mortem: H8 *unions* for the f16 fragments blocked SROA ->
// clang put them in SCRATCH (VGPR 48, hbm_bytes 1.21 GB: 17 unions/tile x
// 16 B/lane x 64 lanes x 32768 tiles = ~557 MB each way, matching counters).
// Fix: build fragments 100% in registers:
//   cvt_pkrtz pair -> shufflevector merge -> bit_cast to MFMA operand type.
// Everything else from round 1 kept: branchless i-chains + final cndmask,
// biases consumed directly as MFMA C operands, L3 C = b2v cancelled via eb.
// ---------------------------------------------------------------------------

typedef _Float16 half8 __attribute__((ext_vector_type(8)));
typedef __fp16  fp16x2 __attribute__((ext_vector_type(2)));
typedef __fp16  fp16x4 __attribute__((ext_vector_type(4)));
typedef __fp16  fp16x8 __attribute__((ext_vector_type(8)));
typedef float floatx16 __attribute__((ext_vector_type(16)));

// relu + f32->f16 (RTZ, packed) for one 8-wide fragment; pure register code.
static __device__ inline half8 relu_pack8(float a0, float a1, float a2, float a3,
                                          float a4, float a5, float a6, float a7) {
    fp16x2 p0 = __builtin_amdgcn_cvt_pkrtz(fmaxf(a0, 0.f), fmaxf(a1, 0.f));
    fp16x2 p1 = __builtin_amdgcn_cvt_pkrtz(fmaxf(a2, 0.f), fmaxf(a3, 0.f));
    fp16x2 p2 = __builtin_amdgcn_cvt_pkrtz(fmaxf(a4, 0.f), fmaxf(a5, 0.f));
    fp16x2 p3 = __builtin_amdgcn_cvt_pkrtz(fmaxf(a6, 0.f), fmaxf(a7, 0.f));
    fp16x4 q0 = __builtin_shufflevector(p0, p1, 0, 1, 2, 3);
    fp16x4 q1 = __builtin_shufflevector(p2, p3, 0, 1, 2, 3);
    fp16x8 r  = __builtin_shufflevector(q0, q1, 0, 1, 2, 3, 4, 5, 6, 7);
    return __builtin_bit_cast(half8, r);
}

__global__ __launch_bounds__(256) void scm_mfma(
    const float* __restrict__ z,
    const float* __restrict__ W1, const float* __restrict__ b1,
    const float* __restrict__ W2, const float* __restrict__ b2,
    const float* __restrict__ W3, const float* __restrict__ b3,
    const int* __restrict__ mask,
    float* __restrict__ out, EpsT ep, int B)
{
    const int lane = threadIdx.x & 63;
    const int hv   = lane >> 5;          // wave half
    const int n    = lane & 31;          // batch row in tile / m index
    const int wid  = blockIdx.x * (blockDim.x >> 6) + (threadIdx.x >> 6);
    const int nw   = gridDim.x * (blockDim.x >> 6);
    const int T    = B >> 5;             // 32-row tiles

    int mk[16];
#pragma unroll
    for (int t = 0; t < 16; ++t) mk[t] = mask[t];     // uniform -> s_load
    int cond[4];
#pragma unroll
    for (int i = 0; i < 4; ++i) cond[i] = mk[i] | mk[4 + i] | mk[8 + i] | mk[12 + i];

    // ---- weight A-fragments (f16), built once per wave ----
    half8 w1m[4], w2f[2], w3f[2];
#pragma unroll
    for (int j = 0; j < 8; ++j) {
        const int k = hv * 8 + j;                     // k in [0,16), natural
        const float w = W1[k * 32 + n];               // W1^T[m=n][k]
#pragma unroll
        for (int i = 0; i < 4; ++i)                   // mask[f=k&3=j&3][i]
            w1m[i][j] = mk[(j & 3) * 4 + i] ? (_Float16)w : (_Float16)0.f;
    }
#pragma unroll
    for (int q = 0; q < 2; ++q)
#pragma unroll
        for (int j = 0; j < 8; ++j) {
            const int row = 16 * q + 4 * hv + 8 * (j >> 2) + (j & 3);  // sigma(k)
            w2f[q][j] = (_Float16)W2[row * 32 + n];
            w3f[q][j] = (n < 8) ? (_Float16)W3[row * 4 + (n & 3)] : (_Float16)0.f;
        }

    // ---- biases in C/D layout (consumed directly as MFMA C operands) ----
    floatx16 b1v, b2v;
#pragma unroll
    for (int r = 0; r < 16; ++r) {
        const int h = (r & 3) + 8 * (r >> 2) + 4 * hv;
        b1v[r] = b1[h];
        b2v[r] = b2[h];
    }
    // eb[s*4+f] = b3[f] + eps[owned col][f] - b2v[f]; b2v is the L3 C-init
    // (rows >= 8 of that product are never read), so this exactly cancels.
    float eb[8];
#pragma unroll
    for (int s2 = 0; s2 < 2; ++s2)
#pragma unroll
        for (int f = 0; f < 4; ++f)
            eb[s2 * 4 + f] = b3[f] + ep.e[(2 * hv + s2) * 4 + f] - b2v[f];

    // ---- grid-stride tile loop with z prefetch ----
    int t = wid;
    float4 za = make_float4(0.f, 0.f, 0.f, 0.f), zb = za;
    if (t < T) {
        const float4* p = reinterpret_cast<const float4*>(z + ((size_t)t * 32 + n) * 16) + hv * 2;
        za = p[0]; zb = p[1];                         // z[n][hv*8 .. hv*8+7]
    }
    while (t < T) {
        const int tn = t + nw;
        float4 na = make_float4(0.f, 0.f, 0.f, 0.f), nb = na;
        if (tn < T) {
            const float4* p = reinterpret_cast<const float4*>(z + ((size_t)tn * 32 + n) * 16) + hv * 2;
            na = p[0]; nb = p[1];
        }

        const float zf[8] = { za.x, za.y, za.z, za.w, zb.x, zb.y, zb.z, zb.w };
        half8 bz;                                     // Z^T B-frag, k natural (RNE)
#pragma unroll
        for (int j = 0; j < 8; ++j) bz[j] = (_Float16)zf[j];

        float ov[8];                                  // default: f32 passthrough
#pragma unroll
        for (int u = 0; u < 8; ++u) ov[u] = zf[u];

#pragma unroll
        for (int i = 0; i < 4; ++i) {
            // L1: K=16, natural order; C = b1v directly
            floatx16 c1 = __builtin_amdgcn_mfma_f32_32x32x16_f16(w1m[i], bz, b1v, 0, 0, 0);
            half8 pa = relu_pack8(c1[0], c1[1], c1[2], c1[3], c1[4], c1[5], c1[6], c1[7]);
            half8 pb = relu_pack8(c1[8], c1[9], c1[10], c1[11], c1[12], c1[13], c1[14], c1[15]);
            // L2: K=32 via sigma-permuted W2 rows; C = b2v directly
            floatx16 c2 = __builtin_amdgcn_mfma_f32_32x32x16_f16(w2f[0], pa, b2v, 0, 0, 0);
            c2 = __builtin_amdgcn_mfma_f32_32x32x16_f16(w2f[1], pb, c2, 0, 0, 0);
            half8 qa = relu_pack8(c2[0], c2[1], c2[2], c2[3], c2[4], c2[5], c2[6], c2[7]);
            half8 qb = relu_pack8(c2[8], c2[9], c2[10], c2[11], c2[12], c2[13], c2[14], c2[15]);
            // L3: W3 duplicated into rows 4-7; C = b2v (cancelled via eb)
            floatx16 c3 = __builtin_amdgcn_mfma_f32_32x32x16_f16(w3f[0], qa, b2v, 0, 0, 0);
            c3 = __builtin_amdgcn_mfma_f32_32x32x16_f16(w3f[1], qb, c3, 0, 0, 0);

            const int  s2 = i & 1;
            const bool ow = ((i >> 1) == hv);         // this half owns cols 2hv,2hv+1
            const bool wr = ow && (cond[i] != 0);
#pragma unroll
            for (int f = 0; f < 4; ++f) {
                const float vv = c3[f] + eb[s2 * 4 + f];
                ov[s2 * 4 + f] = wr ? vv : ov[s2 * 4 + f];
            }
        }

        // all 64 lanes store: lane (hv,n) writes out[n][8hv .. 8hv+7]
        float4* op = reinterpret_cast<float4*>(out + ((size_t)t * 32 + n) * 16 + hv * 8);
        op[0] = make_float4(ov[0], ov[1], ov[2], ov[3]);
        op[1] = make_float4(ov[4], ov[5], ov[6], ov[7]);

        t = tn; za = na; zb = nb;
    }
}

extern "C" void kernel_launch(void* const* d_in, const int* in_sizes, int n_in,
                              void* d_out, int out_size, void* d_ws, size_t ws_size,
                              hipStream_t stream) {
    const float* z  = (const float*)d_in[0];
    // d_in[1] = z_int (dead code in reference)
    const float* W1 = (const float*)d_in[2];
    const float* b1 = (const float*)d_in[3];
    const float* W2 = (const float*)d_in[4];
    const float* b2 = (const float*)d_in[5];
    const float* W3 = (const float*)d_in[6];
    const float* b3 = (const float*)d_in[7];
    const int* mask = (const int*)d_in[8];
    // d_in[9] = I (dead code in reference)
    float* out = (float*)d_out;

    const int B = in_sizes[0] / 16;

    EpsT ep;
    compute_eps(ep.e);   // pure host math, deterministic, capture-safe

    dim3 grid(2048), block(256);   // 8192 waves, grid-stride over B/32 tiles
    hipLaunchKernelGGL(scm_mfma, grid, block, 0, stream,
                       z, W1, b1, W2, b2, W3, b3, mask, out, ep, B);
}

// Round 5
// 185.530 us; speedup vs baseline: 2.3124x; 1.0861x over previous
//
#include <hip/hip_runtime.h>
#include <cmath>
#include <cstdint>
#include <cstring>

// ---------------------------------------------------------------------------
// eps = jax.random.normal(jax.random.key(42), (4,4)) reproduced on HOST.
// (verified PASS in earlier rounds): counter (0,e), XOR-fold the 2x32
// outputs; bits>>9|0x3f800000 -> [1,2); affine to [nextafter(-1,0), 1);
// sqrt(2)*erfinv.
// ---------------------------------------------------------------------------

static inline uint32_t rotl32(uint32_t v, int r) { return (v << r) | (v >> (32 - r)); }

static void threefry2x32_42(uint32_t x0, uint32_t x1, uint32_t& o0, uint32_t& o1) {
    const uint32_t k0 = 0u, k1 = 42u;
    const uint32_t ks[3] = { k0, k1, k0 ^ k1 ^ 0x1BD11BDAu };
    static const int R[8] = { 13, 15, 26, 6, 17, 29, 16, 24 };
    x0 += ks[0];
    x1 += ks[1];
    for (int g = 1; g <= 5; ++g) {
        const int* rr = &R[((g - 1) & 1) * 4];
        for (int j = 0; j < 4; ++j) {
            x0 += x1;
            x1 = rotl32(x1, rr[j]);
            x1 ^= x0;
        }
        x0 += ks[g % 3];
        x1 += ks[(g + 1) % 3] + (uint32_t)g;
    }
    o0 = x0;
    o1 = x1;
}

static double erfinv_d(double x) {
    float xf = (float)x;
    float w = -logf((1.0f - xf) * (1.0f + xf));
    float p;
    if (w < 5.0f) {
        w -= 2.5f;
        p = 2.81022636e-08f;
        p = fmaf(p, w, 3.43273939e-07f);
        p = fmaf(p, w, -3.5233877e-06f);
        p = fmaf(p, w, -4.39150654e-06f);
        p = fmaf(p, w, 0.00021858087f);
        p = fmaf(p, w, -0.00125372503f);
        p = fmaf(p, w, -0.00417768164f);
        p = fmaf(p, w, 0.246640727f);
        p = fmaf(p, w, 1.50140941f);
    } else {
        w = sqrtf(w) - 3.0f;
        p = -0.000200214257f;
        p = fmaf(p, w, 0.000100950558f);
        p = fmaf(p, w, 0.00134934322f);
        p = fmaf(p, w, -0.00367342844f);
        p = fmaf(p, w, 0.00573950773f);
        p = fmaf(p, w, -0.0076224613f);
        p = fmaf(p, w, 0.00943887047f);
        p = fmaf(p, w, 1.00167406f);
        p = fmaf(p, w, 2.83297682f);
    }
    double y = (double)(p * xf);
    const double c = 1.1283791670955126;
    for (int it = 0; it < 3; ++it) {
        double err = erf(y) - x;
        y -= err / (c * exp(-y * y));
    }
    return y;
}

struct EpsT { float e[16]; };

static void compute_eps(float* e) {
    const float lo = -0.99999994f;
    for (int i = 0; i < 16; ++i) {
        uint32_t a, b;
        threefry2x32_42(0u, (uint32_t)i, a, b);
        uint32_t bits = a ^ b;
        uint32_t fb = (bits >> 9) | 0x3f800000u;
        float f;
        memcpy(&f, &fb, 4);
        float u = f - 1.0f;
        float v = u * 2.0f + lo;
        if (v < lo) v = lo;
        e[i] = (float)(sqrt(2.0) * erfinv_d((double)v));
    }
}

// ---------------------------------------------------------------------------
// Shuffle-free MFMA chain via K-permutation (layouts verified end-to-end):
//   C/D: lane (hv=lane>>5, n=lane&31), reg r -> D[row][n], row=(r&3)+8*(r>>2)+4hv
//   A:   lane (hv, m=lane&31), elem j  -> A[m][k=8hv+j]
//   B:   lane (hv, n=lane&31), elem j  -> B[k=8hv+j][n]
// Layers 2/3 relabel K with sigma(16q+8hv+j)=16q+4hv+8*(j>>2)+(j&3) so reg r of
// the previous C/D is exactly elem j=r&7 of B-fragment q=r>>3 (no cross-lane).
// W3 duplicated into output rows 4-7 so both wave halves hold f=0..3 in regs
// 0-3. Mask folds into the W1 A-frag via per-chain SGPR bitmasks.
//
// Round-4 (occupancy attack): counters showed latency-bound (VALU 10%/SIMD,
// MFMA 3%/SIMD, HBM 17%) with OccupancyPercent tracking 1/VGPR: 2 waves/SIMD
// at arch-VGPR 72 => unified arch+acc footprint is in the 129-256 bucket.
//  * __launch_bounds__(256,4): force total regs <= 128 -> 4 waves/SIMD
//  * mask -> readfirstlane SGPRs; W1 kept as ONE packed frag (4 VGPR) and
//    masked per chain with SGPR bitmasks (v_and v,s,v) -> -12 persistent VGPR
//  * grid 1024 (8 tiles/wave): resident set 4 blocks/CU, prologue amortized
//  * nontemporal stores: don't victimize L3-resident z with the 64MB stream
//    (NOTE: must go through clang ext_vector float4, not HIP_vector_type)
// ---------------------------------------------------------------------------

typedef _Float16 half8 __attribute__((ext_vector_type(8)));
typedef __fp16  fp16x2 __attribute__((ext_vector_type(2)));
typedef __fp16  fp16x4 __attribute__((ext_vector_type(4)));
typedef __fp16  fp16x8 __attribute__((ext_vector_type(8)));
typedef uint32_t uint32x4 __attribute__((ext_vector_type(4)));
typedef float floatx4 __attribute__((ext_vector_type(4)));
typedef float floatx16 __attribute__((ext_vector_type(16)));

// relu + f32->f16 (RTZ, packed) for one 8-wide fragment; pure register code.
static __device__ inline half8 relu_pack8(float a0, float a1, float a2, float a3,
                                          float a4, float a5, float a6, float a7) {
    fp16x2 p0 = __builtin_amdgcn_cvt_pkrtz(fmaxf(a0, 0.f), fmaxf(a1, 0.f));
    fp16x2 p1 = __builtin_amdgcn_cvt_pkrtz(fmaxf(a2, 0.f), fmaxf(a3, 0.f));
    fp16x2 p2 = __builtin_amdgcn_cvt_pkrtz(fmaxf(a4, 0.f), fmaxf(a5, 0.f));
    fp16x2 p3 = __builtin_amdgcn_cvt_pkrtz(fmaxf(a6, 0.f), fmaxf(a7, 0.f));
    fp16x4 q0 = __builtin_shufflevector(p0, p1, 0, 1, 2, 3);
    fp16x4 q1 = __builtin_shufflevector(p2, p3, 0, 1, 2, 3);
    fp16x8 r  = __builtin_shufflevector(q0, q1, 0, 1, 2, 3, 4, 5, 6, 7);
    return __builtin_bit_cast(half8, r);
}

__global__ __launch_bounds__(256, 4) void scm_mfma(
    const float* __restrict__ z,
    const float* __restrict__ W1, const float* __restrict__ b1,
    const float* __restrict__ W2, const float* __restrict__ b2,
    const float* __restrict__ W3, const float* __restrict__ b3,
    const int* __restrict__ mask,
    float* __restrict__ out, EpsT ep, int B)
{
    const int lane = threadIdx.x & 63;
    const int hv   = lane >> 5;          // wave half
    const int n    = lane & 31;          // batch row in tile / m index
    const int wid  = blockIdx.x * (blockDim.x >> 6) + (threadIdx.x >> 6);
    const int nw   = gridDim.x * (blockDim.x >> 6);
    const int T    = B >> 5;             // 32-row tiles

    // ---- mask -> SGPRs (wave-uniform), per-chain f16x2 AND-masks in SGPRs ----
    int mku[16];
#pragma unroll
    for (int t = 0; t < 16; ++t) mku[t] = __builtin_amdgcn_readfirstlane(mask[t]);
    int cond[4];
    uint32_t M01[4], M23[4];             // uniform -> SALU/SGPR
#pragma unroll
    for (int i = 0; i < 4; ++i) {
        cond[i] = mku[i] | mku[4 + i] | mku[8 + i] | mku[12 + i];
        M01[i] = (mku[i]      ? 0x0000FFFFu : 0u) | (mku[4 + i]  ? 0xFFFF0000u : 0u);
        M23[i] = (mku[8 + i]  ? 0x0000FFFFu : 0u) | (mku[12 + i] ? 0xFFFF0000u : 0u);
    }

    // ---- weight fragments (f16), built once per wave ----
    half8 w1, w2f[2], w3f[2];
#pragma unroll
    for (int j = 0; j < 8; ++j)                        // k = 8hv+j, natural
        w1[j] = (_Float16)W1[(hv * 8 + j) * 32 + n];   // W1^T[m=n][k]
    const uint32x4 w1u = __builtin_bit_cast(uint32x4, w1);
#pragma unroll
    for (int q = 0; q < 2; ++q)
#pragma unroll
        for (int j = 0; j < 8; ++j) {
            const int row = 16 * q + 4 * hv + 8 * (j >> 2) + (j & 3);  // sigma(k)
            w2f[q][j] = (_Float16)W2[row * 32 + n];
            w3f[q][j] = (n < 8) ? (_Float16)W3[row * 4 + (n & 3)] : (_Float16)0.f;
        }

    // ---- biases in C/D layout (consumed directly as MFMA C operands) ----
    floatx16 b1v, b2v;
#pragma unroll
    for (int r = 0; r < 16; ++r) {
        const int h = (r & 3) + 8 * (r >> 2) + 4 * hv;
        b1v[r] = b1[h];
        b2v[r] = b2[h];
    }
    // eb[s*4+f] = b3[f] + eps[owned col][f] - b2v[f]; b2v is the L3 C-init
    // (rows >= 8 of that product are never read), so this exactly cancels.
    float eb[8];
#pragma unroll
    for (int s2 = 0; s2 < 2; ++s2)
#pragma unroll
        for (int f = 0; f < 4; ++f)
            eb[s2 * 4 + f] = b3[f] + ep.e[(2 * hv + s2) * 4 + f] - b2v[f];

    // ---- grid-stride tile loop with z prefetch ----
    int t = wid;
    floatx4 za = { 0.f, 0.f, 0.f, 0.f }, zb = za;
    if (t < T) {
        const floatx4* p = reinterpret_cast<const floatx4*>(z + ((size_t)t * 32 + n) * 16) + hv * 2;
        za = p[0]; zb = p[1];                         // z[n][hv*8 .. hv*8+7]
    }
    while (t < T) {
        const int tn = t + nw;
        floatx4 na = { 0.f, 0.f, 0.f, 0.f }, nb = na;
        if (tn < T) {
            const floatx4* p = reinterpret_cast<const floatx4*>(z + ((size_t)tn * 32 + n) * 16) + hv * 2;
            na = p[0]; nb = p[1];
        }

        half8 bz;                                     // Z^T B-frag, k natural (RNE)
        bz[0] = (_Float16)za.x; bz[1] = (_Float16)za.y;
        bz[2] = (_Float16)za.z; bz[3] = (_Float16)za.w;
        bz[4] = (_Float16)zb.x; bz[5] = (_Float16)zb.y;
        bz[6] = (_Float16)zb.z; bz[7] = (_Float16)zb.w;

        float ov[8];                                  // default: f32 passthrough
        ov[0] = za.x; ov[1] = za.y; ov[2] = za.z; ov[3] = za.w;
        ov[4] = zb.x; ov[5] = zb.y; ov[6] = zb.z; ov[7] = zb.w;

#pragma unroll
        for (int i = 0; i < 4; ++i) {
            // per-chain masked W1 A-frag: packed f16 AND with SGPR bitmasks
            uint32x4 wm;
            wm.x = w1u.x & M01[i];
            wm.y = w1u.y & M23[i];
            wm.z = w1u.z & M01[i];
            wm.w = w1u.w & M23[i];
            const half8 w1m = __builtin_bit_cast(half8, wm);
            // L1: K=16, natural order; C = b1v directly
            floatx16 c1 = __builtin_amdgcn_mfma_f32_32x32x16_f16(w1m, bz, b1v, 0, 0, 0);
            half8 pa = relu_pack8(c1[0], c1[1], c1[2], c1[3], c1[4], c1[5], c1[6], c1[7]);
            half8 pb = relu_pack8(c1[8], c1[9], c1[10], c1[11], c1[12], c1[13], c1[14], c1[15]);
            // L2: K=32 via sigma-permuted W2 rows; C = b2v directly
            floatx16 c2 = __builtin_amdgcn_mfma_f32_32x32x16_f16(w2f[0], pa, b2v, 0, 0, 0);
            c2 = __builtin_amdgcn_mfma_f32_32x32x16_f16(w2f[1], pb, c2, 0, 0, 0);
            half8 qa = relu_pack8(c2[0], c2[1], c2[2], c2[3], c2[4], c2[5], c2[6], c2[7]);
            half8 qb = relu_pack8(c2[8], c2[9], c2[10], c2[11], c2[12], c2[13], c2[14], c2[15]);
            // L3: W3 duplicated into rows 4-7; C = b2v (cancelled via eb)
            floatx16 c3 = __builtin_amdgcn_mfma_f32_32x32x16_f16(w3f[0], qa, b2v, 0, 0, 0);
            c3 = __builtin_amdgcn_mfma_f32_32x32x16_f16(w3f[1], qb, c3, 0, 0, 0);

            const int  s2 = i & 1;
            const bool ow = ((i >> 1) == hv);         // this half owns cols 2hv,2hv+1
            const bool wr = ow && (cond[i] != 0);
#pragma unroll
            for (int f = 0; f < 4; ++f) {
                const float vv = c3[f] + eb[s2 * 4 + f];
                ov[s2 * 4 + f] = wr ? vv : ov[s2 * 4 + f];
            }
        }

        // all 64 lanes store: lane (hv,n) writes out[n][8hv .. 8hv+7]
        // nontemporal: pure streaming output, keep L2/L3 for z
        floatx4* op = reinterpret_cast<floatx4*>(out + ((size_t)t * 32 + n) * 16 + hv * 8);
        floatx4 o0 = { ov[0], ov[1], ov[2], ov[3] };
        floatx4 o1 = { ov[4], ov[5], ov[6], ov[7] };
        __builtin_nontemporal_store(o0, op);
        __builtin_nontemporal_store(o1, op + 1);

        t = tn; za = na; zb = nb;
    }
}

extern "C" void kernel_launch(void* const* d_in, const int* in_sizes, int n_in,
                              void* d_out, int out_size, void* d_ws, size_t ws_size,
                              hipStream_t stream) {
    const float* z  = (const float*)d_in[0];
    // d_in[1] = z_int (dead code in reference)
    const float* W1 = (const float*)d_in[2];
    const float* b1 = (const float*)d_in[3];
    const float* W2 = (const float*)d_in[4];
    const float* b2 = (const float*)d_in[5];
    const float* W3 = (const float*)d_in[6];
    const float* b3 = (const float*)d_in[7];
    const int* mask = (const int*)d_in[8];
    // d_in[9] = I (dead code in reference)
    float* out = (float*)d_out;

    const int B = in_sizes[0] / 16;

    EpsT ep;
    compute_eps(ep.e);   // pure host math, deterministic, capture-safe

    // 1024 blocks x 4 waves = 4096 waves; 8 tiles/wave; 4 blocks/CU resident
    dim3 grid(1024), block(256);
    hipLaunchKernelGGL(scm_mfma, grid, block, 0, stream,
                       z, W1, b1, W2, b2, W3, b3, mask, out, ep, B);
}